// Round 7
// baseline (511.787 us; speedup 1.0000x reference)
//
#include <hip/hip_runtime.h>
#include <hip/hip_bf16.h>

// (B,N,D) = (4,4096,256) fp32 in/out.
//  proj3: fused q/k/v projection (3-term fp16-split MFMA), fp16 out,
//         q pre-scaled by log2e.
//  transpose_v: v -> vT[d][n]
//  attn_flash2: QBLK=128 q-rows/block, 8 waves (4 q-groups x 2 col-halves),
//         KV tile = 64 keys staged in 128KB double-buffered LDS as prebuilt
//         MFMA fragments (conflict-free), shared by all waves (8x traffic cut
//         vs QBLK=32). Q single-fp16 in registers. One barrier per iter.
//         128KB static LDS forces 1 block/CU -> compiler targets 2 waves/SIMD
//         -> 256-VGPR budget (kills the 128-reg remat/spill failure of R4-R6).

#define SEQ   4096
#define DIM   256
#define LOG2E 1.4426950408889634f

typedef _Float16 f16;
typedef __attribute__((ext_vector_type(8)))  f16    f16x8;
typedef __attribute__((ext_vector_type(2)))  __fp16 pk16x2;   // cvt_pkrtz native type
typedef __attribute__((ext_vector_type(16))) float  f32x16;

// ---------------------------------------------------------------------------
// Fused projection: out = (X @ W^T + b) * scale, fp16. blockIdx.y selects q/k/v.
// Body identical to verified proj_mfma (rounds 3-6), Q-lo output removed.
// ---------------------------------------------------------------------------
__global__ __launch_bounds__(256) void proj3(
    const float* __restrict__ X,
    const float* __restrict__ Wq, const float* __restrict__ bq,
    const float* __restrict__ Wk, const float* __restrict__ bk,
    const float* __restrict__ Wv, const float* __restrict__ bv,
    f16* __restrict__ outq, f16* __restrict__ outk, f16* __restrict__ outv)
{
    const float* W; const float* bias; f16* out; float scale;
    if (blockIdx.y == 0)      { W = Wq; bias = bq; out = outq; scale = LOG2E; }
    else if (blockIdx.y == 1) { W = Wk; bias = bk; out = outk; scale = 1.f; }
    else                      { W = Wv; bias = bv; out = outv; scale = 1.f; }

    const int w = threadIdx.x >> 6, lane = threadIdx.x & 63;
    const int col = lane & 31, hi = lane >> 5;
    const int m0 = blockIdx.x * 64 + (w & 1) * 32;
    const int e0 = (w >> 1) * 128;

    f32x16 acc[4] = {};
    for (int s = 0; s < 16; ++s) {
        const float* xp = X + (size_t)(m0 + col) * DIM + s * 16 + 8 * hi;
        float xv[8];
        *(float4*)&xv[0] = *(const float4*)xp;
        *(float4*)&xv[4] = *(const float4*)(xp + 4);
        f16x8 xh, xl;
        #pragma unroll
        for (int i = 0; i < 8; ++i) {
            xh[i] = (f16)xv[i];
            xl[i] = (f16)(xv[i] - (float)xh[i]);
        }
        #pragma unroll
        for (int c = 0; c < 4; ++c) {
            const float* wp = W + (size_t)(e0 + c * 32 + col) * DIM + s * 16 + 8 * hi;
            float wv[8];
            *(float4*)&wv[0] = *(const float4*)wp;
            *(float4*)&wv[4] = *(const float4*)(wp + 4);
            f16x8 wh, wl;
            #pragma unroll
            for (int i = 0; i < 8; ++i) {
                wh[i] = (f16)wv[i];
                wl[i] = (f16)(wv[i] - (float)wh[i]);
            }
            acc[c] = __builtin_amdgcn_mfma_f32_32x32x16_f16(xh, wh, acc[c], 0, 0, 0);
            acc[c] = __builtin_amdgcn_mfma_f32_32x32x16_f16(xl, wh, acc[c], 0, 0, 0);
            acc[c] = __builtin_amdgcn_mfma_f32_32x32x16_f16(xh, wl, acc[c], 0, 0, 0);
        }
    }
    #pragma unroll
    for (int c = 0; c < 4; ++c) {
        const int e = e0 + c * 32 + col;
        const float b = bias[e];
        #pragma unroll
        for (int r = 0; r < 16; ++r) {
            const int m = m0 + (r & 3) + 8 * (r >> 2) + 4 * hi;
            out[(size_t)m * DIM + e] = (f16)((acc[c][r] + b) * scale);
        }
    }
}

// ---------------------------------------------------------------------------
// v (fp16 [N][256] per batch) -> vT (fp16 [256][N] per batch)  (verified)
// ---------------------------------------------------------------------------
__global__ void transpose_v(const f16* __restrict__ v, f16* __restrict__ vT)
{
    __shared__ f16 tile[32][33];
    const size_t pp = (size_t)SEQ * DIM;
    const f16* vb = v + blockIdx.z * pp;
    f16* vTb = vT + blockIdx.z * pp;
    const int n0 = blockIdx.x * 32, e0 = blockIdx.y * 32;
    #pragma unroll
    for (int r = 0; r < 4; ++r)
        tile[threadIdx.y + 8 * r][threadIdx.x] =
            vb[(size_t)(n0 + threadIdx.y + 8 * r) * DIM + e0 + threadIdx.x];
    __syncthreads();
    #pragma unroll
    for (int r = 0; r < 4; ++r)
        vTb[(size_t)(e0 + threadIdx.y + 8 * r) * SEQ + n0 + threadIdx.x] =
            tile[threadIdx.x][threadIdx.y + 8 * r];
}

// ---------------------------------------------------------------------------
// Flash attention, QBLK=128, 8 waves. Wave (qg,ch): qg=wid>>1 owns q-rows
// [128qt+32qg, +32); ch=wid&1 owns output cols [128ch, +128).
// Both ch waves compute the same 64x32 S^T (duplicated QK^T avoids any
// cross-wave P exchange; softmax fully wave-private, R5-verified machinery).
// K/V staged in LDS as prebuilt fragments:
//   K frag entry (sl,hi,key): uint4 idx = (sl*2+hi)*64 + key        (2048)
//   V frag entry (cg,s,hi,c): uint4 idx = 2048 + (cg*4+s)*64 + hi*32 + c
// Staging chunk m = wid*8+c covers entries m*64+lane -> identical flat
// expression for K and V; writes/reads all lane-consecutive (conflict-free).
// ---------------------------------------------------------------------------
__global__ __launch_bounds__(512, 2) void attn_flash2(
    const f16* __restrict__ qh, const f16* __restrict__ kh,
    const f16* __restrict__ vT, float* __restrict__ out, int nb)
{
    __shared__ uint4 smem[8192];   // 128 KB: [buf:2][K 2048 | V 2048]

    int qt, b;
    if (nb == 4) {
        const int lin = blockIdx.x;          // 128 blocks
        const int x = lin & 7;               // XCD
        b = x >> 1;                          // 2 XCDs per batch
        qt = 2 * (lin >> 3) + (x & 1);       // [0,32)
    } else { qt = blockIdx.x; b = 0; }

    const size_t pp = (size_t)SEQ * DIM;
    const f16* qhb = qh + b * pp;
    const f16* khb = kh + b * pp;
    const f16* vTb = vT + b * pp;            // [256][4096]
    float* outb = out + b * pp;

    const int wid = threadIdx.x >> 6, lane = threadIdx.x & 63;
    const int col = lane & 31, hi = lane >> 5;
    const int qg = wid >> 1, ch = wid & 1;
    const int q0w = qt * 128 + qg * 32;
    const int nt = 2 * qt + 2;               // 64-key tiles

    // staging helpers (wave-uniform chunk index m; all branches wave-uniform)
    auto issue = [&](uint4* sreg, int key0) {
        #pragma unroll
        for (int c = 0; c < 8; ++c) {
            const int m = wid * 8 + c;
            const f16* src;
            if (m < 32) {                    // K chunk: sl = m>>1, hik = m&1
                src = khb + (size_t)(key0 + lane) * DIM + (m >> 1) * 16 + (m & 1) * 8;
            } else {                         // V chunk: cg = (m-32)>>2, s = (m-32)&3
                const int mm = m - 32;
                src = vTb + (size_t)(32 * (mm >> 2) + col) * SEQ + key0 + 16 * (mm & 3) + 8 * hi;
            }
            sreg[c] = *(const uint4*)src;
        }
    };
    auto commit = [&](const uint4* sreg, int base) {
        #pragma unroll
        for (int c = 0; c < 8; ++c)
            smem[base + (wid * 8 + c) * 64 + lane] = sreg[c];
    };
    // A-frag build from p[base..base+16) (verified cvt_pk + shfl_xor(32))
    float p[32];
    auto build2 = [&](uint4& Alo, uint4& Ahi, int base) {
        uint32_t Wd[8], Od[8];
        #pragma unroll
        for (int jj = 0; jj < 8; ++jj)
            Wd[jj] = __builtin_bit_cast(uint32_t,
                __builtin_amdgcn_cvt_pkrtz(p[base + 2 * jj], p[base + 2 * jj + 1]));
        #pragma unroll
        for (int jj = 0; jj < 8; ++jj)
            Od[jj] = (uint32_t)__shfl_xor((int)Wd[jj], 32);
        if (hi == 0) {
            Alo.x = Wd[0]; Alo.y = Wd[1]; Alo.z = Od[0]; Alo.w = Od[1];
            Ahi.x = Wd[4]; Ahi.y = Wd[5]; Ahi.z = Od[4]; Ahi.w = Od[5];
        } else {
            Alo.x = Od[2]; Alo.y = Od[3]; Alo.z = Wd[2]; Alo.w = Wd[3];
            Ahi.x = Od[6]; Ahi.y = Od[7]; Ahi.z = Wd[6]; Ahi.w = Wd[7];
        }
    };

    // Q fragments resident (single fp16; 64 VGPRs)
    f16x8 qhf[16];
    #pragma unroll
    for (int sl = 0; sl < 16; ++sl)
        qhf[sl] = *(const f16x8*)(qhb + (size_t)(q0w + col) * DIM + sl * 16 + 8 * hi);

    {   // prologue: stage tile 0
        uint4 sreg[8];
        issue(sreg, 0);
        commit(sreg, 0);
    }
    __syncthreads();

    float m_run = -1e28f, l_run = 0.f;
    f32x16 oacc[4] = {};                     // cols 128ch + 32cg + col
    int buf = 0;

    for (int t = 0; t < nt; ++t) {
        const int bb = buf * 4096;

        // ---- QK^T: S^T (64 keys x 32 q), 4 independent MFMA chains ----
        f32x16 s0a = {}, s0b = {}, s1a = {}, s1b = {};
        #pragma unroll
        for (int sl = 0; sl < 16; ++sl) {
            const f16x8 k0 = __builtin_bit_cast(f16x8, smem[bb + (sl * 2 + hi) * 64 + col]);
            const f16x8 k1 = __builtin_bit_cast(f16x8, smem[bb + (sl * 2 + hi) * 64 + 32 + col]);
            if (sl & 1) {
                s0b = __builtin_amdgcn_mfma_f32_32x32x16_f16(k0, qhf[sl], s0b, 0, 0, 0);
                s1b = __builtin_amdgcn_mfma_f32_32x32x16_f16(k1, qhf[sl], s1b, 0, 0, 0);
            } else {
                s0a = __builtin_amdgcn_mfma_f32_32x32x16_f16(k0, qhf[sl], s0a, 0, 0, 0);
                s1a = __builtin_amdgcn_mfma_f32_32x32x16_f16(k1, qhf[sl], s1a, 0, 0, 0);
            }
        }

        // ---- issue next-tile global loads (hidden under softmax+PV) ----
        uint4 sreg[8];
        const bool do_stage = (t + 1 < nt);
        if (do_stage) issue(sreg, 64 * (t + 1));

        // ---- mask + wave-private softmax (per lane: q-row = q0w+col) ----
        float pmax = -1e30f;
        float sv[32];
        #pragma unroll
        for (int r = 0; r < 16; ++r) {
            const int kg = 64 * t + (r & 3) + 8 * (r >> 2) + 4 * hi;
            const float x0 = (kg <= q0w + col)      ? (s0a[r] + s0b[r]) : -1e30f;
            const float x1 = (kg + 32 <= q0w + col) ? (s1a[r] + s1b[r]) : -1e30f;
            sv[r] = x0; sv[16 + r] = x1;
            pmax = fmaxf(pmax, fmaxf(x0, x1));
        }
        pmax = fmaxf(pmax, __shfl_xor(pmax, 32));
        pmax = fmaxf(pmax, -1e28f);          // guard: all-masked rows -> p = 0
        if (__any(pmax > m_run + 11.5415603f)) {   // defer-max, 8-nat window
            const float m_new = fmaxf(m_run, pmax);
            const float sc = exp2f(m_run - m_new);
            m_run = m_new;
            l_run *= sc;
            #pragma unroll
            for (int r = 0; r < 16; ++r) {
                const int qr = (r & 3) + 8 * (r >> 2) + 4 * hi;
                const float scr = __shfl(sc, qr | (lane & 32));
                oacc[0][r] *= scr; oacc[1][r] *= scr;
                oacc[2][r] *= scr; oacc[3][r] *= scr;
            }
        }
        float tsum = 0.f;
        #pragma unroll
        for (int r = 0; r < 32; ++r) {
            p[r] = exp2f(sv[r] - m_run);
            tsum += p[r];
        }
        tsum += __shfl_xor(tsum, 32);
        l_run += tsum;

        // ---- P -> A fragments (keys 0-31 and 32-63 of this tile) ----
        uint4 A0, A1, A2, A3;
        build2(A0, A1, 0);
        build2(A2, A3, 16);

        // ---- commit next tile to other buffer (safe: all waves passed the
        //      previous barrier, so no one still reads buf^1) ----
        if (do_stage) commit(sreg, bb ^ 4096);

        // ---- PV: own 128-col half, 16 MFMA ----
        #pragma unroll
        for (int cg = 0; cg < 4; ++cg) {
            const int vbase = bb + 2048 + ((4 * ch + cg) * 4) * 64 + hi * 32 + col;
            const f16x8 v0 = __builtin_bit_cast(f16x8, smem[vbase]);
            const f16x8 v1 = __builtin_bit_cast(f16x8, smem[vbase + 64]);
            const f16x8 v2 = __builtin_bit_cast(f16x8, smem[vbase + 128]);
            const f16x8 v3 = __builtin_bit_cast(f16x8, smem[vbase + 192]);
            oacc[cg] = __builtin_amdgcn_mfma_f32_32x32x16_f16(__builtin_bit_cast(f16x8, A0), v0, oacc[cg], 0, 0, 0);
            oacc[cg] = __builtin_amdgcn_mfma_f32_32x32x16_f16(__builtin_bit_cast(f16x8, A1), v1, oacc[cg], 0, 0, 0);
            oacc[cg] = __builtin_amdgcn_mfma_f32_32x32x16_f16(__builtin_bit_cast(f16x8, A2), v2, oacc[cg], 0, 0, 0);
            oacc[cg] = __builtin_amdgcn_mfma_f32_32x32x16_f16(__builtin_bit_cast(f16x8, A3), v3, oacc[cg], 0, 0, 0);
        }

        __syncthreads();                     // ONE barrier per iter
        buf ^= 1;
    }

    // epilogue: divide by l, store fp32
    const float linv = 1.f / l_run;
    #pragma unroll
    for (int r = 0; r < 16; ++r) {
        const int qr = (r & 3) + 8 * (r >> 2) + 4 * hi;
        const float lr = __shfl(linv, qr | (lane & 32));
        const int n = q0w + qr;
        #pragma unroll
        for (int cg = 0; cg < 4; ++cg)
            outb[(size_t)n * DIM + ch * 128 + cg * 32 + col] = oacc[cg][r] * lr;
    }
}

// ---------------------------------------------------------------------------
extern "C" void kernel_launch(void* const* d_in, const int* in_sizes, int n_in,
                              void* d_out, int out_size, void* d_ws, size_t ws_size,
                              hipStream_t stream) {
    const float* x  = (const float*)d_in[0];
    const float* Wq = (const float*)d_in[1];
    const float* bq = (const float*)d_in[2];
    const float* Wk = (const float*)d_in[3];
    const float* bk = (const float*)d_in[4];
    const float* Wv = (const float*)d_in[5];
    const float* bv = (const float*)d_in[6];
    float* out = (float*)d_out;

    const size_t PP = (size_t)SEQ * DIM;            // per-batch plane elems
    const size_t FULL = 4 * PP;                     // all-batch plane elems

    if (ws_size >= FULL * 2 * 4) {
        // full-batch path: 4 fp16 planes (qh, kh, vv, vT) = 67 MB
        f16* qh = (f16*)d_ws;
        f16* kh = qh + FULL;
        f16* vv = kh + FULL;
        f16* vT = vv + FULL;
        proj3<<<dim3(256, 3), 256, 0, stream>>>(x, Wq, bq, Wk, bk, Wv, bv, qh, kh, vv);
        transpose_v<<<dim3(128, 8, 4), dim3(32, 8), 0, stream>>>(vv, vT);
        attn_flash2<<<dim3(128), 512, 0, stream>>>(qh, kh, vT, out, 4);
    } else {
        // per-batch fallback (8.4 MB of ws)
        f16* qh = (f16*)d_ws;
        f16* kh = qh + PP;
        f16* vv = kh + PP;
        f16* vT = vv + PP;
        for (int b = 0; b < 4; ++b) {
            const float* xb = x + b * PP;
            proj3<<<dim3(64, 3), 256, 0, stream>>>(xb, Wq, bq, Wk, bk, Wv, bv, qh, kh, vv);
            transpose_v<<<dim3(128, 8, 1), dim3(32, 8), 0, stream>>>(vv, vT);
            attn_flash2<<<dim3(32), 512, 0, stream>>>(qh, kh, vT, out + b * PP, 1);
        }
    }
}

// Round 8
// 331.615 us; speedup vs baseline: 1.5433x; 1.5433x over previous
//
#include <hip/hip_runtime.h>
#include <hip/hip_bf16.h>

// (B,N,D) = (4,4096,256) fp32 in/out.
//  proj3: fused q/k/v projection (3-term fp16-split MFMA), fp16 out,
//         q pre-scaled by log2e.  (verified R3-R7)
//  transpose_v: v -> vT[d][n]    (verified)
//  attn_flash3: 256 blocks x 2 waves (launch_bounds(128,1) -> 256 VGPR,
//         the only config that empirically avoids the 128-reg scratch trap).
//         Causal balance: block processes q-tile qt then 127-qt (equal work).
//         Per 64-key tile: K+V staged ONCE to dbuf LDS via global_load_lds
//         DMA (issued iter t for t+1; never drained at the mid barrier),
//         wave w: QK^T own 32-key half (K frags read once, Q in regs),
//         local softmax -> A-frags -> 4KB P-exchange; bar1 = raw s_barrier
//         + lgkmcnt(0) only; PV col-split; bar2 = __syncthreads().

#define SEQ   4096
#define DIM   256
#define LOG2E 1.4426950408889634f

typedef _Float16 f16;
typedef __attribute__((ext_vector_type(8)))  f16    f16x8;
typedef __attribute__((ext_vector_type(2)))  __fp16 pk16x2;
typedef __attribute__((ext_vector_type(16))) float  f32x16;

typedef const __attribute__((address_space(1))) unsigned int GAS;
typedef __attribute__((address_space(3)))       unsigned int LAS;
#define DMA16(g, l) __builtin_amdgcn_global_load_lds((GAS*)(g), (LAS*)(l), 16, 0, 0)

// ---------------------------------------------------------------------------
// Fused projection (verified). out = (X @ W^T + b) * scale, fp16.
// ---------------------------------------------------------------------------
__global__ __launch_bounds__(256) void proj3(
    const float* __restrict__ X,
    const float* __restrict__ Wq, const float* __restrict__ bq,
    const float* __restrict__ Wk, const float* __restrict__ bk,
    const float* __restrict__ Wv, const float* __restrict__ bv,
    f16* __restrict__ outq, f16* __restrict__ outk, f16* __restrict__ outv)
{
    const float* W; const float* bias; f16* out; float scale;
    if (blockIdx.y == 0)      { W = Wq; bias = bq; out = outq; scale = LOG2E; }
    else if (blockIdx.y == 1) { W = Wk; bias = bk; out = outk; scale = 1.f; }
    else                      { W = Wv; bias = bv; out = outv; scale = 1.f; }

    const int w = threadIdx.x >> 6, lane = threadIdx.x & 63;
    const int col = lane & 31, hi = lane >> 5;
    const int m0 = blockIdx.x * 64 + (w & 1) * 32;
    const int e0 = (w >> 1) * 128;

    f32x16 acc[4] = {};
    for (int s = 0; s < 16; ++s) {
        const float* xp = X + (size_t)(m0 + col) * DIM + s * 16 + 8 * hi;
        float xv[8];
        *(float4*)&xv[0] = *(const float4*)xp;
        *(float4*)&xv[4] = *(const float4*)(xp + 4);
        f16x8 xh, xl;
        #pragma unroll
        for (int i = 0; i < 8; ++i) {
            xh[i] = (f16)xv[i];
            xl[i] = (f16)(xv[i] - (float)xh[i]);
        }
        #pragma unroll
        for (int c = 0; c < 4; ++c) {
            const float* wp = W + (size_t)(e0 + c * 32 + col) * DIM + s * 16 + 8 * hi;
            float wv[8];
            *(float4*)&wv[0] = *(const float4*)wp;
            *(float4*)&wv[4] = *(const float4*)(wp + 4);
            f16x8 wh, wl;
            #pragma unroll
            for (int i = 0; i < 8; ++i) {
                wh[i] = (f16)wv[i];
                wl[i] = (f16)(wv[i] - (float)wh[i]);
            }
            acc[c] = __builtin_amdgcn_mfma_f32_32x32x16_f16(xh, wh, acc[c], 0, 0, 0);
            acc[c] = __builtin_amdgcn_mfma_f32_32x32x16_f16(xl, wh, acc[c], 0, 0, 0);
            acc[c] = __builtin_amdgcn_mfma_f32_32x32x16_f16(xh, wl, acc[c], 0, 0, 0);
        }
    }
    #pragma unroll
    for (int c = 0; c < 4; ++c) {
        const int e = e0 + c * 32 + col;
        const float b = bias[e];
        #pragma unroll
        for (int r = 0; r < 16; ++r) {
            const int m = m0 + (r & 3) + 8 * (r >> 2) + 4 * hi;
            out[(size_t)m * DIM + e] = (f16)((acc[c][r] + b) * scale);
        }
    }
}

// ---------------------------------------------------------------------------
// v (fp16 [N][256] per batch) -> vT (fp16 [256][N] per batch)  (verified)
// ---------------------------------------------------------------------------
__global__ void transpose_v(const f16* __restrict__ v, f16* __restrict__ vT)
{
    __shared__ f16 tile[32][33];
    const size_t pp = (size_t)SEQ * DIM;
    const f16* vb = v + blockIdx.z * pp;
    f16* vTb = vT + blockIdx.z * pp;
    const int n0 = blockIdx.x * 32, e0 = blockIdx.y * 32;
    #pragma unroll
    for (int r = 0; r < 4; ++r)
        tile[threadIdx.y + 8 * r][threadIdx.x] =
            vb[(size_t)(n0 + threadIdx.y + 8 * r) * DIM + e0 + threadIdx.x];
    __syncthreads();
    #pragma unroll
    for (int r = 0; r < 4; ++r)
        vTb[(size_t)(e0 + threadIdx.y + 8 * r) * SEQ + n0 + threadIdx.x] =
            tile[threadIdx.x][threadIdx.y + 8 * r];
}

// ---------------------------------------------------------------------------
// DMA-stage one 64-key tile (K 32KB + V 32KB) into smem[bufbase..].
// K frag entry (sl,hi,key):  idx = (sl*2+hi)*64 + key            [0,2048)
// V frag entry (cg,s,hi,c):  idx = 2048 + (cg*4+s)*64 + hi*32+c  [2048,4096)
// wave0 stages K (chunk m: src byte = (key0+lane)*512 + m*16, dst m*64),
// wave1 stages V (chunk mm: cg=mm>>2, s=mm&3).
// ---------------------------------------------------------------------------
__device__ __forceinline__ void stage_tile(
    const f16* khb, const f16* vTb, uint4* smem,
    int bufbase, int key0, int wid, int lane, int col, int hi)
{
    if (wid == 0) {
        const char* kp = (const char*)khb + (size_t)(key0 + lane) * 512;
        #pragma unroll
        for (int m = 0; m < 32; ++m)
            DMA16(kp + m * 16, smem + bufbase + m * 64);
    } else {
        const char* vp = (const char*)vTb + (size_t)col * 8192
                         + (size_t)key0 * 2 + hi * 16;
        #pragma unroll
        for (int mm = 0; mm < 32; ++mm)
            DMA16(vp + (size_t)(mm >> 2) * 32 * 8192 + (mm & 3) * 32,
                  smem + bufbase + 2048 + mm * 64);
    }
}

// ---------------------------------------------------------------------------
// Flash attention: 2 waves, 32 q-rows per pass, 2 complementary passes.
// ---------------------------------------------------------------------------
__global__ __launch_bounds__(128, 1) void attn_flash3(
    const f16* __restrict__ qh, const f16* __restrict__ kh,
    const f16* __restrict__ vT, float* __restrict__ out, int nb)
{
    __shared__ uint4 smem[8192];      // 2 x (K 2048 | V 2048) = 128 KB
    __shared__ uint4 Pex[256];        // A-frags: (s*2+hi)*32+col, 4 KB
    __shared__ float mlbuf[2][2][32]; // [m|l][wave][q]

    int qtA, b;
    if (nb == 4) {
        const int lin = blockIdx.x;       // 256 blocks
        const int x = lin & 7;            // XCD
        b = x >> 1;                       // 2 XCDs per batch
        qtA = (x & 1) * 32 + (lin >> 3);  // [0,64)
    } else { qtA = blockIdx.x; b = 0; }   // grid 64

    const size_t pp = (size_t)SEQ * DIM;
    const f16* qhb = qh + b * pp;
    const f16* khb = kh + b * pp;
    const f16* vTb = vT + b * pp;   // [256][4096]
    float* outb = out + b * pp;

    const int wid = threadIdx.x >> 6, lane = threadIdx.x & 63;
    const int col = lane & 31, hi = lane >> 5;

    for (int pass = 0; pass < 2; ++pass) {
        const int qt = pass ? (127 - qtA) : qtA;
        const int q0 = qt * 32;
        const int nt = (qt + 2) >> 1;     // 64-key tiles

        // Q fragments resident (single fp16, 64 VGPRs)
        f16x8 qhf[16];
        #pragma unroll
        for (int sl = 0; sl < 16; ++sl)
            qhf[sl] = *(const f16x8*)(qhb + (size_t)(q0 + col) * DIM + sl * 16 + 8 * hi);

        stage_tile(khb, vTb, smem, 0, 0, wid, lane, col, hi);
        __syncthreads();                  // drains DMA for tile 0

        float m_run = -1e28f, l_run = 0.f;
        f32x16 oacc[4] = {};              // cols 128*wid + 32*cg + col

        for (int t = 0; t < nt; ++t) {
            const int bb = (t & 1) * 4096;

            // ---- issue DMA for tile t+1 (stays in flight across bar1) ----
            if (t + 1 < nt)
                stage_tile(khb, vTb, smem, bb ^ 4096, 64 * (t + 1), wid, lane, col, hi);

            // ---- QK^T: own 32-key half, K frags from LDS (read once) ----
            f32x16 s1 = {}, s2 = {};
            #pragma unroll
            for (int sl = 0; sl < 16; ++sl) {
                const f16x8 kf = __builtin_bit_cast(f16x8,
                    smem[bb + (sl * 2 + hi) * 64 + 32 * wid + col]);
                if (sl & 1) s2 = __builtin_amdgcn_mfma_f32_32x32x16_f16(kf, qhf[sl], s2, 0, 0, 0);
                else        s1 = __builtin_amdgcn_mfma_f32_32x32x16_f16(kf, qhf[sl], s1, 0, 0, 0);
            }

            // ---- mask + wave-local softmax (q-row = q0+col per lane) ----
            float sv[16];
            float pmax = -1e30f, tsum = 0.f;
            #pragma unroll
            for (int r = 0; r < 16; ++r) {
                const int kg = 64 * t + 32 * wid + (r & 3) + 8 * (r >> 2) + 4 * hi;
                const float x = (kg <= q0 + col) ? (s1[r] + s2[r]) : -1e30f;
                sv[r] = x;
                pmax = fmaxf(pmax, x);
            }
            pmax = fmaxf(pmax, __shfl_xor(pmax, 32));
            pmax = fmaxf(pmax, -1e28f);   // all-masked half -> p = 0
            {
                float p[16];
                #pragma unroll
                for (int r = 0; r < 16; ++r) {
                    p[r] = exp2f(sv[r] - pmax);
                    tsum += p[r];
                }
                tsum += __shfl_xor(tsum, 32);
                // A-frag build (verified cvt_pk + shfl_xor(32))
                uint32_t Wd[8], Od[8];
                #pragma unroll
                for (int jj = 0; jj < 8; ++jj)
                    Wd[jj] = __builtin_bit_cast(uint32_t,
                        __builtin_amdgcn_cvt_pkrtz(p[2 * jj], p[2 * jj + 1]));
                #pragma unroll
                for (int jj = 0; jj < 8; ++jj)
                    Od[jj] = (uint32_t)__shfl_xor((int)Wd[jj], 32);
                uint4 A0, A1;
                if (hi == 0) {
                    A0.x = Wd[0]; A0.y = Wd[1]; A0.z = Od[0]; A0.w = Od[1];
                    A1.x = Wd[4]; A1.y = Wd[5]; A1.z = Od[4]; A1.w = Od[5];
                } else {
                    A0.x = Od[2]; A0.y = Od[3]; A0.z = Wd[2]; A0.w = Wd[3];
                    A1.x = Od[6]; A1.y = Od[7]; A1.z = Wd[6]; A1.w = Wd[7];
                }
                Pex[((2 * wid + 0) * 2 + hi) * 32 + col] = A0;  // keys [32w,+16)
                Pex[((2 * wid + 1) * 2 + hi) * 32 + col] = A1;  // keys [32w+16,+16)
            }
            if (lane < 32) {
                mlbuf[0][wid][col] = pmax;
                mlbuf[1][wid][col] = tsum;
            }
            // ---- bar1: DS-drain only; DMAs for t+1 stay in flight ----
            asm volatile("s_waitcnt lgkmcnt(0)" ::: "memory");
            __builtin_amdgcn_sched_barrier(0);
            __builtin_amdgcn_s_barrier();
            __builtin_amdgcn_sched_barrier(0);

            // ---- merge m/l (per q-row = col), defer-max rescale ----
            const float mw0 = mlbuf[0][0][col], mw1 = mlbuf[0][1][col];
            const float tw0 = mlbuf[1][0][col], tw1 = mlbuf[1][1][col];
            const float mt = fmaxf(mw0, mw1);
            float scale = 1.f;
            if (__any(mt > m_run + 11.5415603f)) {   // 8-nat window (log2)
                const float m_new = fmaxf(m_run, mt);
                scale = exp2f(m_run - m_new);
                m_run = m_new;
                #pragma unroll
                for (int r = 0; r < 16; ++r) {
                    const int qr = (r & 3) + 8 * (r >> 2) + 4 * hi;
                    const float scr = __shfl(scale, qr | (lane & 32));
                    oacc[0][r] *= scr; oacc[1][r] *= scr;
                    oacc[2][r] *= scr; oacc[3][r] *= scr;
                }
            }
            const float c0 = exp2f(mw0 - m_run);
            const float c1 = exp2f(mw1 - m_run);
            l_run = l_run * scale + tw0 * c0 + tw1 * c1;
            const f16 ch[2] = {(f16)c0, (f16)c1};

            // ---- PV: own 128-col half, V frags read once ----
            #pragma unroll
            for (int s4 = 0; s4 < 4; ++s4) {
                f16x8 af = __builtin_bit_cast(f16x8, Pex[(s4 * 2 + hi) * 32 + col]);
                af = af * ch[s4 >> 1];     // producer-wave corr (per q-row lane)
                #pragma unroll
                for (int cg = 0; cg < 4; ++cg) {
                    const f16x8 vf = __builtin_bit_cast(f16x8,
                        smem[bb + 2048 + ((4 * wid + cg) * 4 + s4) * 64 + lane]);
                    oacc[cg] = __builtin_amdgcn_mfma_f32_32x32x16_f16(af, vf, oacc[cg], 0, 0, 0);
                }
            }

            __syncthreads();   // bar2: drains own DMA (t+1) + orders LDS reuse
        }

        // ---- epilogue: divide by l, store fp32 ----
        const float linv = 1.f / l_run;
        #pragma unroll
        for (int r = 0; r < 16; ++r) {
            const int qr = (r & 3) + 8 * (r >> 2) + 4 * hi;
            const float lr = __shfl(linv, qr | (lane & 32));
            const int n = q0 + qr;
            #pragma unroll
            for (int cg = 0; cg < 4; ++cg)
                outb[(size_t)n * DIM + 128 * wid + 32 * cg + col] = oacc[cg][r] * lr;
        }
        __syncthreads();       // LDS quiesced before next pass prologue
    }
}

// ---------------------------------------------------------------------------
extern "C" void kernel_launch(void* const* d_in, const int* in_sizes, int n_in,
                              void* d_out, int out_size, void* d_ws, size_t ws_size,
                              hipStream_t stream) {
    const float* x  = (const float*)d_in[0];
    const float* Wq = (const float*)d_in[1];
    const float* bq = (const float*)d_in[2];
    const float* Wk = (const float*)d_in[3];
    const float* bk = (const float*)d_in[4];
    const float* Wv = (const float*)d_in[5];
    const float* bv = (const float*)d_in[6];
    float* out = (float*)d_out;

    const size_t PP = (size_t)SEQ * DIM;
    const size_t FULL = 4 * PP;

    if (ws_size >= FULL * 2 * 4) {
        f16* qh = (f16*)d_ws;
        f16* kh = qh + FULL;
        f16* vv = kh + FULL;
        f16* vT = vv + FULL;
        proj3<<<dim3(256, 3), 256, 0, stream>>>(x, Wq, bq, Wk, bk, Wv, bv, qh, kh, vv);
        transpose_v<<<dim3(128, 8, 4), dim3(32, 8), 0, stream>>>(vv, vT);
        attn_flash3<<<dim3(256), 128, 0, stream>>>(qh, kh, vT, out, 4);
    } else {
        f16* qh = (f16*)d_ws;
        f16* kh = qh + PP;
        f16* vv = kh + PP;
        f16* vT = vv + PP;
        for (int b = 0; b < 4; ++b) {
            const float* xb = x + b * PP;
            proj3<<<dim3(64, 3), 256, 0, stream>>>(xb, Wq, bq, Wk, bk, Wv, bv, qh, kh, vv);
            transpose_v<<<dim3(128, 8, 1), dim3(32, 8), 0, stream>>>(vv, vT);
            attn_flash3<<<dim3(64), 128, 0, stream>>>(qh, kh, vT, out + b * PP, 1);
        }
    }
}

// Round 9
// 259.028 us; speedup vs baseline: 1.9758x; 1.2802x over previous
//
#include <hip/hip_runtime.h>
#include <hip/hip_bf16.h>

// (B,N,D) = (4,4096,256) fp32 in/out.
//  proj3: fused q/k/v projection (3-term fp16-split MFMA), fp16 out,
//         q pre-scaled by log2e.  (verified R3-R8)
//  transpose_v: v -> vT[d][n]    (verified)
//  attn_flash4: 256 blocks x 2 waves (launch_bounds(128,1) -> 216+ VGPR,
//         empirically the only non-spilling config). Causal balance:
//         block does q-tile qt then 127-qt. Per 64-key tile: K+V staged to
//         dbuf LDS via global_load_lds with CONTIGUOUS 1KB sources and
//         XOR-preswizzled chunk order (slot = chunk ^ (row&7)) so MFMA
//         fragment reads are bank-conflict-free (R8's per-lane gather DMA
//         was 4x L2 over-fetch + serialized line requests -> 10K cyc/iter).
//         QK^T own 32-key half; local softmax -> A-frags -> 4KB P-exchange;
//         bar1 = raw s_barrier + lgkmcnt(0) only (DMA stays in flight);
//         PV col-split; bar2 = __syncthreads().

#define SEQ   4096
#define DIM   256
#define LOG2E 1.4426950408889634f

typedef _Float16 f16;
typedef __attribute__((ext_vector_type(8)))  f16    f16x8;
typedef __attribute__((ext_vector_type(2)))  __fp16 pk16x2;
typedef __attribute__((ext_vector_type(16))) float  f32x16;

typedef const __attribute__((address_space(1))) unsigned int GAS;
typedef __attribute__((address_space(3)))       unsigned int LAS;
#define DMA16(g, l) __builtin_amdgcn_global_load_lds((GAS*)(g), (LAS*)(l), 16, 0, 0)

// ---------------------------------------------------------------------------
// Fused projection (verified). out = (X @ W^T + b) * scale, fp16.
// ---------------------------------------------------------------------------
__global__ __launch_bounds__(256) void proj3(
    const float* __restrict__ X,
    const float* __restrict__ Wq, const float* __restrict__ bq,
    const float* __restrict__ Wk, const float* __restrict__ bk,
    const float* __restrict__ Wv, const float* __restrict__ bv,
    f16* __restrict__ outq, f16* __restrict__ outk, f16* __restrict__ outv)
{
    const float* W; const float* bias; f16* out; float scale;
    if (blockIdx.y == 0)      { W = Wq; bias = bq; out = outq; scale = LOG2E; }
    else if (blockIdx.y == 1) { W = Wk; bias = bk; out = outk; scale = 1.f; }
    else                      { W = Wv; bias = bv; out = outv; scale = 1.f; }

    const int w = threadIdx.x >> 6, lane = threadIdx.x & 63;
    const int col = lane & 31, hi = lane >> 5;
    const int m0 = blockIdx.x * 64 + (w & 1) * 32;
    const int e0 = (w >> 1) * 128;

    f32x16 acc[4] = {};
    for (int s = 0; s < 16; ++s) {
        const float* xp = X + (size_t)(m0 + col) * DIM + s * 16 + 8 * hi;
        float xv[8];
        *(float4*)&xv[0] = *(const float4*)xp;
        *(float4*)&xv[4] = *(const float4*)(xp + 4);
        f16x8 xh, xl;
        #pragma unroll
        for (int i = 0; i < 8; ++i) {
            xh[i] = (f16)xv[i];
            xl[i] = (f16)(xv[i] - (float)xh[i]);
        }
        #pragma unroll
        for (int c = 0; c < 4; ++c) {
            const float* wp = W + (size_t)(e0 + c * 32 + col) * DIM + s * 16 + 8 * hi;
            float wv[8];
            *(float4*)&wv[0] = *(const float4*)wp;
            *(float4*)&wv[4] = *(const float4*)(wp + 4);
            f16x8 wh, wl;
            #pragma unroll
            for (int i = 0; i < 8; ++i) {
                wh[i] = (f16)wv[i];
                wl[i] = (f16)(wv[i] - (float)wh[i]);
            }
            acc[c] = __builtin_amdgcn_mfma_f32_32x32x16_f16(xh, wh, acc[c], 0, 0, 0);
            acc[c] = __builtin_amdgcn_mfma_f32_32x32x16_f16(xl, wh, acc[c], 0, 0, 0);
            acc[c] = __builtin_amdgcn_mfma_f32_32x32x16_f16(xh, wl, acc[c], 0, 0, 0);
        }
    }
    #pragma unroll
    for (int c = 0; c < 4; ++c) {
        const int e = e0 + c * 32 + col;
        const float b = bias[e];
        #pragma unroll
        for (int r = 0; r < 16; ++r) {
            const int m = m0 + (r & 3) + 8 * (r >> 2) + 4 * hi;
            out[(size_t)m * DIM + e] = (f16)((acc[c][r] + b) * scale);
        }
    }
}

// ---------------------------------------------------------------------------
// v (fp16 [N][256] per batch) -> vT (fp16 [256][N] per batch)  (verified)
// ---------------------------------------------------------------------------
__global__ void transpose_v(const f16* __restrict__ v, f16* __restrict__ vT)
{
    __shared__ f16 tile[32][33];
    const size_t pp = (size_t)SEQ * DIM;
    const f16* vb = v + blockIdx.z * pp;
    f16* vTb = vT + blockIdx.z * pp;
    const int n0 = blockIdx.x * 32, e0 = blockIdx.y * 32;
    #pragma unroll
    for (int r = 0; r < 4; ++r)
        tile[threadIdx.y + 8 * r][threadIdx.x] =
            vb[(size_t)(n0 + threadIdx.y + 8 * r) * DIM + e0 + threadIdx.x];
    __syncthreads();
    #pragma unroll
    for (int r = 0; r < 4; ++r)
        vTb[(size_t)(e0 + threadIdx.y + 8 * r) * SEQ + n0 + threadIdx.x] =
            tile[threadIdx.x][threadIdx.y + 8 * r];
}

// ---------------------------------------------------------------------------
// LDS layout per buffer (uint4 units):
//   K: rows 0..63 (keys), 32 chunks each: idx = row*32 + (chunk ^ (row&7))
//      (chunk = kdim-byte/16 = 2*sl + hi)
//   V: rows 0..255 (dims), 8 chunks each: idx = 2048 + row*8 + (chunk ^ (row&7))
//      (chunk = keylocal-byte/16 = 2*s4 + hi)
// DMA: instruction m moves a CONTIGUOUS 1KB global span; the source chunk
// order is pre-permuted by the same XOR so LDS ends up swizzled (G21).
// ---------------------------------------------------------------------------
__global__ __launch_bounds__(128, 1) void attn_flash4(
    const f16* __restrict__ qh, const f16* __restrict__ kh,
    const f16* __restrict__ vT, float* __restrict__ out, int nb)
{
    __shared__ uint4 smem[8192];      // 2 x (K 2048 | V 2048) = 128 KB
    __shared__ uint4 Pex[256];        // A-frags: (s*2+hi)*32+col, 4 KB
    __shared__ float mlbuf[2][2][32]; // [m|l][wave][q]

    int qtA, b;
    if (nb == 4) {
        const int lin = blockIdx.x;       // 256 blocks
        const int x = lin & 7;            // XCD
        b = x >> 1;                       // 2 XCDs per batch
        qtA = (x & 1) * 32 + (lin >> 3);  // [0,64)
    } else { qtA = blockIdx.x; b = 0; }   // grid 64

    const size_t pp = (size_t)SEQ * DIM;
    const f16* qhb = qh + b * pp;
    const char* kbyte = (const char*)(kh + b * pp);   // [4096][512B]
    const char* vbyte = (const char*)(vT + b * pp);   // [256][8192B]
    float* outb = out + b * pp;

    const int wid = threadIdx.x >> 6, lane = threadIdx.x & 63;
    const int col = lane & 31, hi = lane >> 5;
    const int e7 = col & 7;               // read-side swizzle key (row&7 == col&7)

    // ---- loop-invariant per-lane DMA source offsets ----
    // K instr m: rows {2m, 2m+1}; lane covers row 2m+(lane>>5), slot lane&31,
    //   src chunk c = slot ^ (row&7); (row&7) = (2(m&3) + (lane>>5)) & 7.
    int kloff[4];
    #pragma unroll
    for (int j = 0; j < 4; ++j)
        kloff[j] = hi * 512 + (col ^ ((2 * j + hi) & 7)) * 16;
    // V instr m: rows {8m..8m+7}; lane covers row 8m+(lane>>3), slot lane&7,
    //   src chunk c = slot ^ (row&7); (row&7) = (lane>>3)&7 (m-independent).
    const int vloff = (lane >> 3) * 8192 + ((lane & 7) ^ ((lane >> 3) & 7)) * 16;

    for (int pass = 0; pass < 2; ++pass) {
        const int qt = pass ? (127 - qtA) : qtA;
        const int q0 = qt * 32;
        const int nt = (qt + 2) >> 1;     // 64-key tiles

        // Q fragments resident (single fp16, 64 VGPRs)
        f16x8 qhf[16];
        #pragma unroll
        for (int sl = 0; sl < 16; ++sl)
            qhf[sl] = *(const f16x8*)(qhb + (size_t)(q0 + col) * DIM + sl * 16 + 8 * hi);

        // ---- prologue: stage tile 0 (wave0: K, wave1: V) ----
        {
            if (wid == 0) {
                #pragma unroll
                for (int m = 0; m < 32; ++m)
                    DMA16(kbyte + m * 1024 + kloff[m & 3], smem + m * 64);
            } else {
                #pragma unroll
                for (int m = 0; m < 32; ++m)
                    DMA16(vbyte + (size_t)m * 65536 + vloff, smem + 2048 + m * 64);
            }
        }
        __syncthreads();                  // drains DMA for tile 0

        float m_run = -1e28f, l_run = 0.f;
        f32x16 oacc[4] = {};              // cols 128*wid + 32*cg + col

        for (int t = 0; t < nt; ++t) {
            const int bb = (t & 1) * 4096;

            // ---- issue DMA for tile t+1 (in flight across bar1) ----
            if (t + 1 < nt) {
                const int key0 = 64 * (t + 1);
                uint4* dst = smem + (bb ^ 4096);
                if (wid == 0) {
                    const char* kp = kbyte + (size_t)key0 * 512;
                    #pragma unroll
                    for (int m = 0; m < 32; ++m)
                        DMA16(kp + m * 1024 + kloff[m & 3], dst + m * 64);
                } else {
                    const char* vp = vbyte + (size_t)key0 * 2;
                    #pragma unroll
                    for (int m = 0; m < 32; ++m)
                        DMA16(vp + (size_t)m * 65536 + vloff, dst + 2048 + m * 64);
                }
            }

            // ---- QK^T: own 32-key half, K frags from swizzled LDS ----
            const int krow = (32 * wid + col) * 32;
            f32x16 s1 = {}, s2 = {};
            #pragma unroll
            for (int sl = 0; sl < 16; ++sl) {
                const f16x8 kf = __builtin_bit_cast(f16x8,
                    smem[bb + krow + ((2 * sl + hi) ^ e7)]);
                if (sl & 1) s2 = __builtin_amdgcn_mfma_f32_32x32x16_f16(kf, qhf[sl], s2, 0, 0, 0);
                else        s1 = __builtin_amdgcn_mfma_f32_32x32x16_f16(kf, qhf[sl], s1, 0, 0, 0);
            }

            // ---- mask + wave-local softmax (q-row = q0+col per lane) ----
            float sv[16];
            float pmax = -1e30f, tsum = 0.f;
            #pragma unroll
            for (int r = 0; r < 16; ++r) {
                const int kg = 64 * t + 32 * wid + (r & 3) + 8 * (r >> 2) + 4 * hi;
                const float x = (kg <= q0 + col) ? (s1[r] + s2[r]) : -1e30f;
                sv[r] = x;
                pmax = fmaxf(pmax, x);
            }
            pmax = fmaxf(pmax, __shfl_xor(pmax, 32));
            pmax = fmaxf(pmax, -1e28f);   // all-masked half -> p = 0
            {
                float p[16];
                #pragma unroll
                for (int r = 0; r < 16; ++r) {
                    p[r] = exp2f(sv[r] - pmax);
                    tsum += p[r];
                }
                tsum += __shfl_xor(tsum, 32);
                // A-frag build (verified cvt_pk + shfl_xor(32))
                uint32_t Wd[8], Od[8];
                #pragma unroll
                for (int jj = 0; jj < 8; ++jj)
                    Wd[jj] = __builtin_bit_cast(uint32_t,
                        __builtin_amdgcn_cvt_pkrtz(p[2 * jj], p[2 * jj + 1]));
                #pragma unroll
                for (int jj = 0; jj < 8; ++jj)
                    Od[jj] = (uint32_t)__shfl_xor((int)Wd[jj], 32);
                uint4 A0, A1;
                if (hi == 0) {
                    A0.x = Wd[0]; A0.y = Wd[1]; A0.z = Od[0]; A0.w = Od[1];
                    A1.x = Wd[4]; A1.y = Wd[5]; A1.z = Od[4]; A1.w = Od[5];
                } else {
                    A0.x = Od[2]; A0.y = Od[3]; A0.z = Wd[2]; A0.w = Wd[3];
                    A1.x = Od[6]; A1.y = Od[7]; A1.z = Wd[6]; A1.w = Wd[7];
                }
                Pex[((2 * wid + 0) * 2 + hi) * 32 + col] = A0;  // keys [32w,+16)
                Pex[((2 * wid + 1) * 2 + hi) * 32 + col] = A1;  // keys [32w+16,+16)
            }
            if (lane < 32) {
                mlbuf[0][wid][col] = pmax;
                mlbuf[1][wid][col] = tsum;
            }
            // ---- bar1: DS-drain only; DMAs for t+1 stay in flight ----
            asm volatile("s_waitcnt lgkmcnt(0)" ::: "memory");
            __builtin_amdgcn_sched_barrier(0);
            __builtin_amdgcn_s_barrier();
            __builtin_amdgcn_sched_barrier(0);

            // ---- merge m/l (per q-row = col), defer-max rescale ----
            const float mw0 = mlbuf[0][0][col], mw1 = mlbuf[0][1][col];
            const float tw0 = mlbuf[1][0][col], tw1 = mlbuf[1][1][col];
            const float mt = fmaxf(mw0, mw1);
            float scale = 1.f;
            if (__any(mt > m_run + 11.5415603f)) {   // 8-nat window (log2)
                const float m_new = fmaxf(m_run, mt);
                scale = exp2f(m_run - m_new);
                m_run = m_new;
                #pragma unroll
                for (int r = 0; r < 16; ++r) {
                    const int qr = (r & 3) + 8 * (r >> 2) + 4 * hi;
                    const float scr = __shfl(scale, qr | (lane & 32));
                    oacc[0][r] *= scr; oacc[1][r] *= scr;
                    oacc[2][r] *= scr; oacc[3][r] *= scr;
                }
            }
            const float c0 = exp2f(mw0 - m_run);
            const float c1 = exp2f(mw1 - m_run);
            l_run = l_run * scale + tw0 * c0 + tw1 * c1;
            const f16 ch[2] = {(f16)c0, (f16)c1};

            // ---- PV: own 128-col half, V frags from swizzled LDS ----
            #pragma unroll
            for (int s4 = 0; s4 < 4; ++s4) {
                f16x8 af = __builtin_bit_cast(f16x8, Pex[(s4 * 2 + hi) * 32 + col]);
                af = af * ch[s4 >> 1];     // producer-wave corr (per q-row lane)
                #pragma unroll
                for (int cg = 0; cg < 4; ++cg) {
                    const int vrow = 128 * wid + 32 * cg + col;   // vrow&7 == e7
                    const f16x8 vf = __builtin_bit_cast(f16x8,
                        smem[bb + 2048 + vrow * 8 + ((2 * s4 + hi) ^ e7)]);
                    oacc[cg] = __builtin_amdgcn_mfma_f32_32x32x16_f16(af, vf, oacc[cg], 0, 0, 0);
                }
            }

            __syncthreads();   // bar2: drains own DMA (t+1) + orders LDS reuse
        }

        // ---- epilogue: divide by l, store fp32 ----
        const float linv = 1.f / l_run;
        #pragma unroll
        for (int r = 0; r < 16; ++r) {
            const int qr = (r & 3) + 8 * (r >> 2) + 4 * hi;
            const float lr = __shfl(linv, qr | (lane & 32));
            const int n = q0 + qr;
            #pragma unroll
            for (int cg = 0; cg < 4; ++cg)
                outb[(size_t)n * DIM + 128 * wid + 32 * cg + col] = oacc[cg][r] * lr;
        }
        __syncthreads();       // LDS quiesced before next pass prologue
    }
}

// ---------------------------------------------------------------------------
extern "C" void kernel_launch(void* const* d_in, const int* in_sizes, int n_in,
                              void* d_out, int out_size, void* d_ws, size_t ws_size,
                              hipStream_t stream) {
    const float* x  = (const float*)d_in[0];
    const float* Wq = (const float*)d_in[1];
    const float* bq = (const float*)d_in[2];
    const float* Wk = (const float*)d_in[3];
    const float* bk = (const float*)d_in[4];
    const float* Wv = (const float*)d_in[5];
    const float* bv = (const float*)d_in[6];
    float* out = (float*)d_out;

    const size_t PP = (size_t)SEQ * DIM;
    const size_t FULL = 4 * PP;

    if (ws_size >= FULL * 2 * 4) {
        f16* qh = (f16*)d_ws;
        f16* kh = qh + FULL;
        f16* vv = kh + FULL;
        f16* vT = vv + FULL;
        proj3<<<dim3(256, 3), 256, 0, stream>>>(x, Wq, bq, Wk, bk, Wv, bv, qh, kh, vv);
        transpose_v<<<dim3(128, 8, 4), dim3(32, 8), 0, stream>>>(vv, vT);
        attn_flash4<<<dim3(256), 128, 0, stream>>>(qh, kh, vT, out, 4);
    } else {
        f16* qh = (f16*)d_ws;
        f16* kh = qh + PP;
        f16* vv = kh + PP;
        f16* vT = vv + PP;
        for (int b = 0; b < 4; ++b) {
            const float* xb = x + b * PP;
            proj3<<<dim3(64, 3), 256, 0, stream>>>(xb, Wq, bq, Wk, bk, Wv, bv, qh, kh, vv);
            transpose_v<<<dim3(128, 8, 1), dim3(32, 8), 0, stream>>>(vv, vT);
            attn_flash4<<<dim3(64), 128, 0, stream>>>(qh, kh, vT, out + b * PP, 1);
        }
    }
}

// Round 10
// 250.274 us; speedup vs baseline: 2.0449x; 1.0350x over previous
//
#include <hip/hip_runtime.h>
#include <hip/hip_bf16.h>

// (B,N,D) = (4,4096,256) fp32 in/out.
//  proj3: fused q/k/v projection (3-term fp16-split MFMA), fp16 out,
//         q pre-scaled by log2e.  (verified R3-R9)
//  transpose_v: v -> vT[d][n]    (verified)
//  attn_flash5: 256 blocks x 4 waves (256 thr, launch_bounds(256,1) ->
//         256-VGPR budget). Block j owns q-rows [64j,64j+64) as TWO
//         independent 32-row sub-blocks (sub = wid>>1), each run by 2 waves
//         with R9's verified machinery (key-half QK^T, wave-local softmax,
//         A-frag P-exchange, defer-max, col-half PV). K/V 64-key tiles
//         staged ONCE per block into dbuf LDS via contiguous-source DMA
//         (split across all 4 waves); sub0's final overshoot tile is fully
//         masked (verified guard -> exact no-op). Fixes R9's half-idle CU
//         (2 waves on 2 of 4 SIMDs -> 4 waves on 4 SIMDs, 256 blocks).

#define SEQ   4096
#define DIM   256
#define LOG2E 1.4426950408889634f

typedef _Float16 f16;
typedef __attribute__((ext_vector_type(8)))  f16    f16x8;
typedef __attribute__((ext_vector_type(2)))  __fp16 pk16x2;
typedef __attribute__((ext_vector_type(16))) float  f32x16;

typedef const __attribute__((address_space(1))) unsigned int GAS;
typedef __attribute__((address_space(3)))       unsigned int LAS;
#define DMA16(g, l) __builtin_amdgcn_global_load_lds((GAS*)(g), (LAS*)(l), 16, 0, 0)

// ---------------------------------------------------------------------------
// Fused projection (verified). out = (X @ W^T + b) * scale, fp16.
// ---------------------------------------------------------------------------
__global__ __launch_bounds__(256) void proj3(
    const float* __restrict__ X,
    const float* __restrict__ Wq, const float* __restrict__ bq,
    const float* __restrict__ Wk, const float* __restrict__ bk,
    const float* __restrict__ Wv, const float* __restrict__ bv,
    f16* __restrict__ outq, f16* __restrict__ outk, f16* __restrict__ outv)
{
    const float* W; const float* bias; f16* out; float scale;
    if (blockIdx.y == 0)      { W = Wq; bias = bq; out = outq; scale = LOG2E; }
    else if (blockIdx.y == 1) { W = Wk; bias = bk; out = outk; scale = 1.f; }
    else                      { W = Wv; bias = bv; out = outv; scale = 1.f; }

    const int w = threadIdx.x >> 6, lane = threadIdx.x & 63;
    const int col = lane & 31, hi = lane >> 5;
    const int m0 = blockIdx.x * 64 + (w & 1) * 32;
    const int e0 = (w >> 1) * 128;

    f32x16 acc[4] = {};
    for (int s = 0; s < 16; ++s) {
        const float* xp = X + (size_t)(m0 + col) * DIM + s * 16 + 8 * hi;
        float xv[8];
        *(float4*)&xv[0] = *(const float4*)xp;
        *(float4*)&xv[4] = *(const float4*)(xp + 4);
        f16x8 xh, xl;
        #pragma unroll
        for (int i = 0; i < 8; ++i) {
            xh[i] = (f16)xv[i];
            xl[i] = (f16)(xv[i] - (float)xh[i]);
        }
        #pragma unroll
        for (int c = 0; c < 4; ++c) {
            const float* wp = W + (size_t)(e0 + c * 32 + col) * DIM + s * 16 + 8 * hi;
            float wv[8];
            *(float4*)&wv[0] = *(const float4*)wp;
            *(float4*)&wv[4] = *(const float4*)(wp + 4);
            f16x8 wh, wl;
            #pragma unroll
            for (int i = 0; i < 8; ++i) {
                wh[i] = (f16)wv[i];
                wl[i] = (f16)(wv[i] - (float)wh[i]);
            }
            acc[c] = __builtin_amdgcn_mfma_f32_32x32x16_f16(xh, wh, acc[c], 0, 0, 0);
            acc[c] = __builtin_amdgcn_mfma_f32_32x32x16_f16(xl, wh, acc[c], 0, 0, 0);
            acc[c] = __builtin_amdgcn_mfma_f32_32x32x16_f16(xh, wl, acc[c], 0, 0, 0);
        }
    }
    #pragma unroll
    for (int c = 0; c < 4; ++c) {
        const int e = e0 + c * 32 + col;
        const float b = bias[e];
        #pragma unroll
        for (int r = 0; r < 16; ++r) {
            const int m = m0 + (r & 3) + 8 * (r >> 2) + 4 * hi;
            out[(size_t)m * DIM + e] = (f16)((acc[c][r] + b) * scale);
        }
    }
}

// ---------------------------------------------------------------------------
// v (fp16 [N][256] per batch) -> vT (fp16 [256][N] per batch)  (verified)
// ---------------------------------------------------------------------------
__global__ void transpose_v(const f16* __restrict__ v, f16* __restrict__ vT)
{
    __shared__ f16 tile[32][33];
    const size_t pp = (size_t)SEQ * DIM;
    const f16* vb = v + blockIdx.z * pp;
    f16* vTb = vT + blockIdx.z * pp;
    const int n0 = blockIdx.x * 32, e0 = blockIdx.y * 32;
    #pragma unroll
    for (int r = 0; r < 4; ++r)
        tile[threadIdx.y + 8 * r][threadIdx.x] =
            vb[(size_t)(n0 + threadIdx.y + 8 * r) * DIM + e0 + threadIdx.x];
    __syncthreads();
    #pragma unroll
    for (int r = 0; r < 4; ++r)
        vTb[(size_t)(e0 + threadIdx.y + 8 * r) * SEQ + n0 + threadIdx.x] =
            tile[threadIdx.x][threadIdx.y + 8 * r];
}

// ---------------------------------------------------------------------------
// attn_flash5. LDS layout per KV buffer (uint4 units), same as R9 (verified):
//   K: [64 keys][32 chunks], idx = key*32 + (chunk ^ (key&7))
//   V: [256 dims][8 chunks], idx = 2048 + vrow*8 + (chunk ^ (vrow&7))
// DMA instr = contiguous 1KB global span, chunk order pre-permuted (G21).
// ---------------------------------------------------------------------------
__global__ __launch_bounds__(256, 1) void attn_flash5(
    const f16* __restrict__ qh, const f16* __restrict__ kh,
    const f16* __restrict__ vT, float* __restrict__ out, int nb)
{
    __shared__ uint4 smem[8192];         // 2 x (K 2048 | V 2048) = 128 KB
    __shared__ uint4 Pex[2][256];        // per sub: A-frags (s*2+hi)*32+col, 8 KB
    __shared__ float mlbuf[2][2][2][32]; // [sub][m|l][kq][q]

    int j, b;
    if (nb == 4) {
        const int lin = blockIdx.x;       // 256 blocks
        const int x = lin & 7;            // XCD
        b = x >> 1;                       // 2 XCDs per batch
        j = (x & 1) * 32 + (lin >> 3);    // [0,64): 64-row group
    } else { j = blockIdx.x; b = 0; }     // grid 64

    const size_t pp = (size_t)SEQ * DIM;
    const f16* qhb = qh + b * pp;
    const char* kbyte = (const char*)(kh + b * pp);   // [4096][512B]
    const char* vbyte = (const char*)(vT + b * pp);   // [256][8192B]
    float* outb = out + b * pp;

    const int wid = threadIdx.x >> 6, lane = threadIdx.x & 63;
    const int col = lane & 31, hi = lane >> 5;
    const int sub = wid >> 1;             // which 32-row sub-block
    const int kq = wid & 1;               // key-half role (QK^T) = col-half (PV)
    const int e7 = col & 7;
    const int q0w = 64 * j + 32 * sub;    // this wave's q-rows
    const int nt = j + 1;                 // 64-key tiles (sub0's last is masked)

    // ---- loop-invariant per-lane DMA source offsets (verified R9) ----
    int kloff[4];
    #pragma unroll
    for (int jj = 0; jj < 4; ++jj)
        kloff[jj] = hi * 512 + (col ^ ((2 * jj + hi) & 7)) * 16;
    const int vloff = (lane >> 3) * 8192 + ((lane & 7) ^ ((lane >> 3) & 7)) * 16;

    // Q fragments resident (single fp16, 64 VGPRs)
    f16x8 qhf[16];
    #pragma unroll
    for (int sl = 0; sl < 16; ++sl)
        qhf[sl] = *(const f16x8*)(qhb + (size_t)(q0w + col) * DIM + sl * 16 + 8 * hi);

    // ---- staging: 64 DMA instrs split over 4 waves ----
    // wave 0,1: K instrs m=16*wid+i; wave 2,3: V instrs m=16*(wid-2)+i.
    #define STAGE(dstbase, key0)                                               \
        do {                                                                   \
            if (wid < 2) {                                                     \
                const char* kp = kbyte + (size_t)(key0) * 512;                 \
                _Pragma("unroll")                                              \
                for (int i = 0; i < 16; ++i) {                                 \
                    const int m = 16 * wid + i;                                \
                    DMA16(kp + m * 1024 + kloff[m & 3], smem + (dstbase) + m * 64); \
                }                                                              \
            } else {                                                           \
                const char* vp = vbyte + (size_t)(key0) * 2;                   \
                _Pragma("unroll")                                              \
                for (int i = 0; i < 16; ++i) {                                 \
                    const int m = 16 * (wid - 2) + i;                          \
                    DMA16(vp + (size_t)m * 65536 + vloff,                      \
                          smem + (dstbase) + 2048 + m * 64);                   \
                }                                                              \
            }                                                                  \
        } while (0)

    STAGE(0, 0);
    __syncthreads();                      // drains DMA for tile 0

    float m_run = -1e28f, l_run = 0.f;
    f32x16 oacc[4] = {};                  // cols 128*kq + 32*cg + col (own sub rows)

    for (int t = 0; t < nt; ++t) {
        const int bb = (t & 1) * 4096;

        // ---- issue DMA for tile t+1 (in flight across bar1) ----
        if (t + 1 < nt) STAGE(bb ^ 4096, 64 * (t + 1));

        // ---- QK^T: own 32-key half, K frags from swizzled LDS ----
        const int krow = (32 * kq + col) * 32;
        f32x16 s1 = {}, s2 = {};
        #pragma unroll
        for (int sl = 0; sl < 16; ++sl) {
            const f16x8 kf = __builtin_bit_cast(f16x8,
                smem[bb + krow + ((2 * sl + hi) ^ e7)]);
            if (sl & 1) s2 = __builtin_amdgcn_mfma_f32_32x32x16_f16(kf, qhf[sl], s2, 0, 0, 0);
            else        s1 = __builtin_amdgcn_mfma_f32_32x32x16_f16(kf, qhf[sl], s1, 0, 0, 0);
        }

        // ---- mask + wave-local softmax (q-row = q0w+col per lane) ----
        float sv[16];
        float pmax = -1e30f, tsum = 0.f;
        #pragma unroll
        for (int r = 0; r < 16; ++r) {
            const int kg = 64 * t + 32 * kq + (r & 3) + 8 * (r >> 2) + 4 * hi;
            const float x = (kg <= q0w + col) ? (s1[r] + s2[r]) : -1e30f;
            sv[r] = x;
            pmax = fmaxf(pmax, x);
        }
        pmax = fmaxf(pmax, __shfl_xor(pmax, 32));
        pmax = fmaxf(pmax, -1e28f);       // fully-masked half -> p = 0 (no-op)
        {
            float p[16];
            #pragma unroll
            for (int r = 0; r < 16; ++r) {
                p[r] = exp2f(sv[r] - pmax);
                tsum += p[r];
            }
            tsum += __shfl_xor(tsum, 32);
            // A-frag build (verified cvt_pk + shfl_xor(32))
            uint32_t Wd[8], Od[8];
            #pragma unroll
            for (int jj = 0; jj < 8; ++jj)
                Wd[jj] = __builtin_bit_cast(uint32_t,
                    __builtin_amdgcn_cvt_pkrtz(p[2 * jj], p[2 * jj + 1]));
            #pragma unroll
            for (int jj = 0; jj < 8; ++jj)
                Od[jj] = (uint32_t)__shfl_xor((int)Wd[jj], 32);
            uint4 A0, A1;
            if (hi == 0) {
                A0.x = Wd[0]; A0.y = Wd[1]; A0.z = Od[0]; A0.w = Od[1];
                A1.x = Wd[4]; A1.y = Wd[5]; A1.z = Od[4]; A1.w = Od[5];
            } else {
                A0.x = Od[2]; A0.y = Od[3]; A0.z = Wd[2]; A0.w = Wd[3];
                A1.x = Od[6]; A1.y = Od[7]; A1.z = Wd[6]; A1.w = Wd[7];
            }
            Pex[sub][((2 * kq + 0) * 2 + hi) * 32 + col] = A0;  // keys [32kq,+16)
            Pex[sub][((2 * kq + 1) * 2 + hi) * 32 + col] = A1;  // keys [32kq+16,+16)
        }
        if (lane < 32) {
            mlbuf[sub][0][kq][col] = pmax;
            mlbuf[sub][1][kq][col] = tsum;
        }
        // ---- bar1: DS-drain only; DMAs for t+1 stay in flight ----
        asm volatile("s_waitcnt lgkmcnt(0)" ::: "memory");
        __builtin_amdgcn_sched_barrier(0);
        __builtin_amdgcn_s_barrier();
        __builtin_amdgcn_sched_barrier(0);

        // ---- merge m/l for own sub (per q-row = col), defer-max rescale ----
        const float mw0 = mlbuf[sub][0][0][col], mw1 = mlbuf[sub][0][1][col];
        const float tw0 = mlbuf[sub][1][0][col], tw1 = mlbuf[sub][1][1][col];
        const float mt = fmaxf(mw0, mw1);
        float scale = 1.f;
        if (__any(mt > m_run + 11.5415603f)) {   // 8-nat window (log2)
            const float m_new = fmaxf(m_run, mt);
            scale = exp2f(m_run - m_new);
            m_run = m_new;
            #pragma unroll
            for (int r = 0; r < 16; ++r) {
                const int qr = (r & 3) + 8 * (r >> 2) + 4 * hi;
                const float scr = __shfl(scale, qr | (lane & 32));
                oacc[0][r] *= scr; oacc[1][r] *= scr;
                oacc[2][r] *= scr; oacc[3][r] *= scr;
            }
        }
        const float c0 = exp2f(mw0 - m_run);
        const float c1 = exp2f(mw1 - m_run);
        l_run = l_run * scale + tw0 * c0 + tw1 * c1;
        const f16 ch[2] = {(f16)c0, (f16)c1};

        // ---- PV: own 128-col half for own sub, V frags from swizzled LDS ----
        #pragma unroll
        for (int s4 = 0; s4 < 4; ++s4) {
            f16x8 af = __builtin_bit_cast(f16x8, Pex[sub][(s4 * 2 + hi) * 32 + col]);
            af = af * ch[s4 >> 1];         // producer-wave corr (per q-row lane)
            #pragma unroll
            for (int cg = 0; cg < 4; ++cg) {
                const int vrow = 128 * kq + 32 * cg + col;   // vrow&7 == e7
                const f16x8 vf = __builtin_bit_cast(f16x8,
                    smem[bb + 2048 + vrow * 8 + ((2 * s4 + hi) ^ e7)]);
                oacc[cg] = __builtin_amdgcn_mfma_f32_32x32x16_f16(af, vf, oacc[cg], 0, 0, 0);
            }
        }

        __syncthreads();   // bar2: drains own DMA (t+1) + orders LDS reuse
    }

    // ---- epilogue: divide by l, store fp32 ----
    const float linv = 1.f / l_run;
    #pragma unroll
    for (int r = 0; r < 16; ++r) {
        const int qr = (r & 3) + 8 * (r >> 2) + 4 * hi;
        const float lr = __shfl(linv, qr | (lane & 32));
        const int n = q0w + qr;
        #pragma unroll
        for (int cg = 0; cg < 4; ++cg)
            outb[(size_t)n * DIM + 128 * kq + 32 * cg + col] = oacc[cg][r] * lr;
    }
    #undef STAGE
}

// ---------------------------------------------------------------------------
extern "C" void kernel_launch(void* const* d_in, const int* in_sizes, int n_in,
                              void* d_out, int out_size, void* d_ws, size_t ws_size,
                              hipStream_t stream) {
    const float* x  = (const float*)d_in[0];
    const float* Wq = (const float*)d_in[1];
    const float* bq = (const float*)d_in[2];
    const float* Wk = (const float*)d_in[3];
    const float* bk = (const float*)d_in[4];
    const float* Wv = (const float*)d_in[5];
    const float* bv = (const float*)d_in[6];
    float* out = (float*)d_out;

    const size_t PP = (size_t)SEQ * DIM;
    const size_t FULL = 4 * PP;

    if (ws_size >= FULL * 2 * 4) {
        f16* qh = (f16*)d_ws;
        f16* kh = qh + FULL;
        f16* vv = kh + FULL;
        f16* vT = vv + FULL;
        proj3<<<dim3(256, 3), 256, 0, stream>>>(x, Wq, bq, Wk, bk, Wv, bv, qh, kh, vv);
        transpose_v<<<dim3(128, 8, 4), dim3(32, 8), 0, stream>>>(vv, vT);
        attn_flash5<<<dim3(256), 256, 0, stream>>>(qh, kh, vT, out, 4);
    } else {
        f16* qh = (f16*)d_ws;
        f16* kh = qh + PP;
        f16* vv = kh + PP;
        f16* vT = vv + PP;
        for (int b = 0; b < 4; ++b) {
            const float* xb = x + b * PP;
            proj3<<<dim3(64, 3), 256, 0, stream>>>(xb, Wq, bq, Wk, bk, Wv, bv, qh, kh, vv);
            transpose_v<<<dim3(128, 8, 1), dim3(32, 8), 0, stream>>>(vv, vT);
            attn_flash5<<<dim3(64), 256, 0, stream>>>(qh, kh, vT, out + b * PP, 1);
        }
    }
}

// Round 11
// 218.860 us; speedup vs baseline: 2.3384x; 1.1435x over previous
//
#include <hip/hip_runtime.h>
#include <hip/hip_bf16.h>

// (B,N,D) = (4,4096,256) fp32 in/out.
//  proj3: fused q/k/v projection (3-term fp16-split MFMA), fp16 out,
//         q pre-scaled by log2e.  (verified R3-R10)
//  transpose_v: v -> vT[d][n]    (verified)
//  attn_flash6: 256 blocks x 8 waves (512 thr) -> 8 waves/CU = 2/SIMD
//         (R9/R10 were 1 wave/SIMD: barrier-locked lone wave exposed the
//         full QK^T->softmax->PV latency chain; per-iter never improved).
//         Block = 64 q-rows = 2 subs x 4 waves. KV tile = 128 keys:
//         wave kq in 0..3 runs the R10-verified 32-key QK^T+softmax
//         verbatim; R5-verified 4-way m/l merge; Pex = 8 slices; PV = own
//         64-col quarter over all 8 slices. K: dbuf LDS via R9-verified
//         contiguous-source pre-swizzled DMA (2x64KB). V: per-wave global
//         register prefetch (R5 pattern). 2 barriers / 128 keys.

#define SEQ   4096
#define DIM   256
#define LOG2E 1.4426950408889634f

typedef _Float16 f16;
typedef __attribute__((ext_vector_type(8)))  f16    f16x8;
typedef __attribute__((ext_vector_type(2)))  __fp16 pk16x2;
typedef __attribute__((ext_vector_type(16))) float  f32x16;

typedef const __attribute__((address_space(1))) unsigned int GAS;
typedef __attribute__((address_space(3)))       unsigned int LAS;
#define DMA16(g, l) __builtin_amdgcn_global_load_lds((GAS*)(g), (LAS*)(l), 16, 0, 0)

// ---------------------------------------------------------------------------
// Fused projection (verified). out = (X @ W^T + b) * scale, fp16.
// ---------------------------------------------------------------------------
__global__ __launch_bounds__(256) void proj3(
    const float* __restrict__ X,
    const float* __restrict__ Wq, const float* __restrict__ bq,
    const float* __restrict__ Wk, const float* __restrict__ bk,
    const float* __restrict__ Wv, const float* __restrict__ bv,
    f16* __restrict__ outq, f16* __restrict__ outk, f16* __restrict__ outv)
{
    const float* W; const float* bias; f16* out; float scale;
    if (blockIdx.y == 0)      { W = Wq; bias = bq; out = outq; scale = LOG2E; }
    else if (blockIdx.y == 1) { W = Wk; bias = bk; out = outk; scale = 1.f; }
    else                      { W = Wv; bias = bv; out = outv; scale = 1.f; }

    const int w = threadIdx.x >> 6, lane = threadIdx.x & 63;
    const int col = lane & 31, hi = lane >> 5;
    const int m0 = blockIdx.x * 64 + (w & 1) * 32;
    const int e0 = (w >> 1) * 128;

    f32x16 acc[4] = {};
    for (int s = 0; s < 16; ++s) {
        const float* xp = X + (size_t)(m0 + col) * DIM + s * 16 + 8 * hi;
        float xv[8];
        *(float4*)&xv[0] = *(const float4*)xp;
        *(float4*)&xv[4] = *(const float4*)(xp + 4);
        f16x8 xh, xl;
        #pragma unroll
        for (int i = 0; i < 8; ++i) {
            xh[i] = (f16)xv[i];
            xl[i] = (f16)(xv[i] - (float)xh[i]);
        }
        #pragma unroll
        for (int c = 0; c < 4; ++c) {
            const float* wp = W + (size_t)(e0 + c * 32 + col) * DIM + s * 16 + 8 * hi;
            float wv[8];
            *(float4*)&wv[0] = *(const float4*)wp;
            *(float4*)&wv[4] = *(const float4*)(wp + 4);
            f16x8 wh, wl;
            #pragma unroll
            for (int i = 0; i < 8; ++i) {
                wh[i] = (f16)wv[i];
                wl[i] = (f16)(wv[i] - (float)wh[i]);
            }
            acc[c] = __builtin_amdgcn_mfma_f32_32x32x16_f16(xh, wh, acc[c], 0, 0, 0);
            acc[c] = __builtin_amdgcn_mfma_f32_32x32x16_f16(xl, wh, acc[c], 0, 0, 0);
            acc[c] = __builtin_amdgcn_mfma_f32_32x32x16_f16(xh, wl, acc[c], 0, 0, 0);
        }
    }
    #pragma unroll
    for (int c = 0; c < 4; ++c) {
        const int e = e0 + c * 32 + col;
        const float b = bias[e];
        #pragma unroll
        for (int r = 0; r < 16; ++r) {
            const int m = m0 + (r & 3) + 8 * (r >> 2) + 4 * hi;
            out[(size_t)m * DIM + e] = (f16)((acc[c][r] + b) * scale);
        }
    }
}

// ---------------------------------------------------------------------------
// v (fp16 [N][256] per batch) -> vT (fp16 [256][N] per batch)  (verified)
// ---------------------------------------------------------------------------
__global__ void transpose_v(const f16* __restrict__ v, f16* __restrict__ vT)
{
    __shared__ f16 tile[32][33];
    const size_t pp = (size_t)SEQ * DIM;
    const f16* vb = v + blockIdx.z * pp;
    f16* vTb = vT + blockIdx.z * pp;
    const int n0 = blockIdx.x * 32, e0 = blockIdx.y * 32;
    #pragma unroll
    for (int r = 0; r < 4; ++r)
        tile[threadIdx.y + 8 * r][threadIdx.x] =
            vb[(size_t)(n0 + threadIdx.y + 8 * r) * DIM + e0 + threadIdx.x];
    __syncthreads();
    #pragma unroll
    for (int r = 0; r < 4; ++r)
        vTb[(size_t)(e0 + threadIdx.y + 8 * r) * SEQ + n0 + threadIdx.x] =
            tile[threadIdx.x][threadIdx.y + 8 * r];
}

// ---------------------------------------------------------------------------
// attn_flash6. K LDS per buffer (uint4 units, 4096 = 64KB):
//   [128 keys][32 chunks], idx = key*32 + (chunk ^ (key&7))
// DMA instr m (0..63) = contiguous 1KB span, rows {2m,2m+1}, chunk order
// pre-permuted (G21; verified R9). Wave w issues m = 8w..8w+7.
// ---------------------------------------------------------------------------
__global__ __launch_bounds__(512, 1) void attn_flash6(
    const f16* __restrict__ qh, const f16* __restrict__ kh,
    const f16* __restrict__ vT, float* __restrict__ out, int nb)
{
    __shared__ uint4 kbuf[2][4096];      // 2 x 64 KB K tiles (128 keys)
    __shared__ uint4 Pex[2][512];        // per sub: slices 0..7, 8 KB each
    __shared__ float mlbuf[2][2][4][32]; // [sub][m|l][kq][q]

    int j, b;
    if (nb == 4) {
        const int lin = blockIdx.x;       // 256 blocks
        const int x = lin & 7;            // XCD
        b = x >> 1;                       // 2 XCDs per batch
        j = (x & 1) * 32 + (lin >> 3);    // [0,64): 64-row group
    } else { j = blockIdx.x; b = 0; }     // grid 64

    const size_t pp = (size_t)SEQ * DIM;
    const f16* qhb = qh + b * pp;
    const char* kbyte = (const char*)(kh + b * pp);   // [4096][512B]
    const f16* vTb = vT + b * pp;                     // [256][4096]
    float* outb = out + b * pp;

    const int wid = threadIdx.x >> 6, lane = threadIdx.x & 63;
    const int col = lane & 31, hi = lane >> 5;
    const int sub = wid >> 2;             // 32-row sub-block (0,1)
    const int kq = wid & 3;               // 32-key quarter / 64-col quarter
    const int e7 = col & 7;
    const int q0w = 64 * j + 32 * sub;    // this wave's q-rows
    const int nt = (j + 2) >> 1;          // 128-key tiles

    // loop-invariant K-DMA per-lane source offsets (verified R9)
    int kloff[4];
    #pragma unroll
    for (int jj = 0; jj < 4; ++jj)
        kloff[jj] = hi * 512 + (col ^ ((2 * jj + hi) & 7)) * 16;

    // Q fragments resident (single fp16, 64 VGPRs)
    f16x8 qhf[16];
    #pragma unroll
    for (int sl = 0; sl < 16; ++sl)
        qhf[sl] = *(const f16x8*)(qhb + (size_t)(q0w + col) * DIM + sl * 16 + 8 * hi);

    // K staging: 64 DMA instrs split over 8 waves
    #define STAGE(buf, key0)                                                   \
        do {                                                                   \
            const char* kp = kbyte + (size_t)(key0) * 512;                     \
            _Pragma("unroll")                                                  \
            for (int i = 0; i < 8; ++i) {                                      \
                const int m = 8 * wid + i;                                     \
                DMA16(kp + m * 1024 + kloff[m & 3], &kbuf[buf][m * 64]);       \
            }                                                                  \
        } while (0)

    STAGE(0, 0);
    __syncthreads();                      // drains DMA for tile 0

    float m_run = -1e28f, l_run = 0.f;
    f32x16 oacc[2] = {};                  // cols 64*kq + 32*cg + col
    const f16* vcol0 = vTb + (size_t)(64 * kq + col) * SEQ + 8 * hi;

    for (int t = 0; t < nt; ++t) {
        const int buf = t & 1;
        const int key0 = t << 7;

        // ---- issue K DMA for tile t+1 (in flight across bar1) ----
        if (t + 1 < nt) STAGE(buf ^ 1, key0 + 128);

        // ---- QK^T: own 32-key quarter, K frags from swizzled LDS ----
        const int krow = (32 * kq + col) * 32;
        f32x16 s1 = {}, s2 = {};
        #pragma unroll
        for (int sl = 0; sl < 16; ++sl) {
            const f16x8 kf = __builtin_bit_cast(f16x8,
                kbuf[buf][krow + ((2 * sl + hi) ^ e7)]);
            if (sl & 1) s2 = __builtin_amdgcn_mfma_f32_32x32x16_f16(kf, qhf[sl], s2, 0, 0, 0);
            else        s1 = __builtin_amdgcn_mfma_f32_32x32x16_f16(kf, qhf[sl], s1, 0, 0, 0);
        }

        // ---- V prefetch A-half (slices 0..3, own 64-col quarter) ----
        f16x8 vfA[2][4];
        #pragma unroll
        for (int cg = 0; cg < 2; ++cg) {
            const f16* vp = vcol0 + (size_t)(32 * cg) * SEQ + key0;
            #pragma unroll
            for (int s = 0; s < 4; ++s) vfA[cg][s] = *(const f16x8*)(vp + 16 * s);
        }

        // ---- mask + wave-local softmax (verified R10 verbatim) ----
        float sv[16];
        float pmax = -1e30f, tsum = 0.f;
        #pragma unroll
        for (int r = 0; r < 16; ++r) {
            const int kg = key0 + 32 * kq + (r & 3) + 8 * (r >> 2) + 4 * hi;
            const float x = (kg <= q0w + col) ? (s1[r] + s2[r]) : -1e30f;
            sv[r] = x;
            pmax = fmaxf(pmax, x);
        }
        pmax = fmaxf(pmax, __shfl_xor(pmax, 32));
        pmax = fmaxf(pmax, -1e28f);       // fully-masked quarter -> p = 0
        {
            float p[16];
            #pragma unroll
            for (int r = 0; r < 16; ++r) {
                p[r] = exp2f(sv[r] - pmax);
                tsum += p[r];
            }
            tsum += __shfl_xor(tsum, 32);
            // A-frag build (verified cvt_pk + shfl_xor(32))
            uint32_t Wd[8], Od[8];
            #pragma unroll
            for (int jj = 0; jj < 8; ++jj)
                Wd[jj] = __builtin_bit_cast(uint32_t,
                    __builtin_amdgcn_cvt_pkrtz(p[2 * jj], p[2 * jj + 1]));
            #pragma unroll
            for (int jj = 0; jj < 8; ++jj)
                Od[jj] = (uint32_t)__shfl_xor((int)Wd[jj], 32);
            uint4 A0, A1;
            if (hi == 0) {
                A0.x = Wd[0]; A0.y = Wd[1]; A0.z = Od[0]; A0.w = Od[1];
                A1.x = Wd[4]; A1.y = Wd[5]; A1.z = Od[4]; A1.w = Od[5];
            } else {
                A0.x = Od[2]; A0.y = Od[3]; A0.z = Wd[2]; A0.w = Wd[3];
                A1.x = Od[6]; A1.y = Od[7]; A1.z = Wd[6]; A1.w = Wd[7];
            }
            Pex[sub][((2 * kq + 0) * 2 + hi) * 32 + col] = A0;  // keys [32kq,+16)
            Pex[sub][((2 * kq + 1) * 2 + hi) * 32 + col] = A1;  // keys [32kq+16,+16)
        }
        if (lane < 32) {
            mlbuf[sub][0][kq][col] = pmax;
            mlbuf[sub][1][kq][col] = tsum;
        }
        // ---- bar1: DS-drain only; K DMAs for t+1 stay in flight ----
        asm volatile("s_waitcnt lgkmcnt(0)" ::: "memory");
        __builtin_amdgcn_sched_barrier(0);
        __builtin_amdgcn_s_barrier();
        __builtin_amdgcn_sched_barrier(0);

        // ---- V prefetch B-half (slices 4..7) ----
        f16x8 vfB[2][4];
        #pragma unroll
        for (int cg = 0; cg < 2; ++cg) {
            const f16* vp = vcol0 + (size_t)(32 * cg) * SEQ + key0 + 64;
            #pragma unroll
            for (int s = 0; s < 4; ++s) vfB[cg][s] = *(const f16x8*)(vp + 16 * s);
        }

        // ---- 4-way m/l merge (verified R5 pattern), defer-max rescale ----
        const float mw0 = mlbuf[sub][0][0][col], mw1 = mlbuf[sub][0][1][col];
        const float mw2 = mlbuf[sub][0][2][col], mw3 = mlbuf[sub][0][3][col];
        const float tw0 = mlbuf[sub][1][0][col], tw1 = mlbuf[sub][1][1][col];
        const float tw2 = mlbuf[sub][1][2][col], tw3 = mlbuf[sub][1][3][col];
        const float mt = fmaxf(fmaxf(mw0, mw1), fmaxf(mw2, mw3));
        float scale = 1.f;
        if (__any(mt > m_run + 11.5415603f)) {   // 8-nat window (log2)
            const float m_new = fmaxf(m_run, mt);
            scale = exp2f(m_run - m_new);
            m_run = m_new;
            #pragma unroll
            for (int r = 0; r < 16; ++r) {
                const int qr = (r & 3) + 8 * (r >> 2) + 4 * hi;
                const float scr = __shfl(scale, qr | (lane & 32));
                oacc[0][r] *= scr; oacc[1][r] *= scr;
            }
        }
        const float c0 = exp2f(mw0 - m_run), c1 = exp2f(mw1 - m_run);
        const float c2 = exp2f(mw2 - m_run), c3 = exp2f(mw3 - m_run);
        l_run = l_run * scale + tw0 * c0 + tw1 * c1 + tw2 * c2 + tw3 * c3;
        const f16 ch[4] = {(f16)c0, (f16)c1, (f16)c2, (f16)c3};

        // ---- PV: 8 slices x own 64-col quarter (V in regs) ----
        #pragma unroll
        for (int s4 = 0; s4 < 4; ++s4) {
            f16x8 af = __builtin_bit_cast(f16x8, Pex[sub][(s4 * 2 + hi) * 32 + col]);
            af = af * ch[s4 >> 1];
            oacc[0] = __builtin_amdgcn_mfma_f32_32x32x16_f16(af, vfA[0][s4], oacc[0], 0, 0, 0);
            oacc[1] = __builtin_amdgcn_mfma_f32_32x32x16_f16(af, vfA[1][s4], oacc[1], 0, 0, 0);
        }
        #pragma unroll
        for (int s4 = 0; s4 < 4; ++s4) {
            f16x8 af = __builtin_bit_cast(f16x8, Pex[sub][((s4 + 4) * 2 + hi) * 32 + col]);
            af = af * ch[2 + (s4 >> 1)];
            oacc[0] = __builtin_amdgcn_mfma_f32_32x32x16_f16(af, vfB[0][s4], oacc[0], 0, 0, 0);
            oacc[1] = __builtin_amdgcn_mfma_f32_32x32x16_f16(af, vfB[1][s4], oacc[1], 0, 0, 0);
        }

        __syncthreads();   // bar2: drains own K DMA (t+1) + orders LDS reuse
    }

    // ---- epilogue: divide by l, store fp32 ----
    const float linv = 1.f / l_run;
    #pragma unroll
    for (int r = 0; r < 16; ++r) {
        const int qr = (r & 3) + 8 * (r >> 2) + 4 * hi;
        const float lr = __shfl(linv, qr | (lane & 32));
        const int n = q0w + qr;
        outb[(size_t)n * DIM + 64 * kq + col]      = oacc[0][r] * lr;
        outb[(size_t)n * DIM + 64 * kq + 32 + col] = oacc[1][r] * lr;
    }
    #undef STAGE
}

// ---------------------------------------------------------------------------
extern "C" void kernel_launch(void* const* d_in, const int* in_sizes, int n_in,
                              void* d_out, int out_size, void* d_ws, size_t ws_size,
                              hipStream_t stream) {
    const float* x  = (const float*)d_in[0];
    const float* Wq = (const float*)d_in[1];
    const float* bq = (const float*)d_in[2];
    const float* Wk = (const float*)d_in[3];
    const float* bk = (const float*)d_in[4];
    const float* Wv = (const float*)d_in[5];
    const float* bv = (const float*)d_in[6];
    float* out = (float*)d_out;

    const size_t PP = (size_t)SEQ * DIM;
    const size_t FULL = 4 * PP;

    if (ws_size >= FULL * 2 * 4) {
        f16* qh = (f16*)d_ws;
        f16* kh = qh + FULL;
        f16* vv = kh + FULL;
        f16* vT = vv + FULL;
        proj3<<<dim3(256, 3), 256, 0, stream>>>(x, Wq, bq, Wk, bk, Wv, bv, qh, kh, vv);
        transpose_v<<<dim3(128, 8, 4), dim3(32, 8), 0, stream>>>(vv, vT);
        attn_flash6<<<dim3(256), 512, 0, stream>>>(qh, kh, vT, out, 4);
    } else {
        f16* qh = (f16*)d_ws;
        f16* kh = qh + PP;
        f16* vv = kh + PP;
        f16* vT = vv + PP;
        for (int b = 0; b < 4; ++b) {
            const float* xb = x + b * PP;
            proj3<<<dim3(64, 3), 256, 0, stream>>>(xb, Wq, bq, Wk, bk, Wv, bv, qh, kh, vv);
            transpose_v<<<dim3(128, 8, 1), dim3(32, 8), 0, stream>>>(vv, vT);
            attn_flash6<<<dim3(64), 512, 0, stream>>>(qh, kh, vT, out + b * PP, 1);
        }
    }
}